// Round 12
// baseline (246.596 us; speedup 1.0000x reference)
//
#include <hip/hip_runtime.h>
#include <math.h>

#define N_RES 4096
#define KNB 32
#define BN_TOTAL 65536  // B*N = 16*4096

typedef float v4f __attribute__((ext_vector_type(4)));
typedef int v4i __attribute__((ext_vector_type(4)));

// ---------------------------------------------------------------------------
// SO(3) projection (cyclic Jacobi on M^T M + Gram-Schmidt for U) — validated.
// ---------------------------------------------------------------------------
template <int p, int q>
__device__ __forceinline__ void jacobi_rot(float S[3][3], float V[3][3]) {
    float apq = S[p][q];
    if (fabsf(apq) > 1e-20f) {
        float app = S[p][p], aqq = S[q][q];
        float tau = (aqq - app) / (2.0f * apq);
        float tt = (tau >= 0.0f ? 1.0f : -1.0f) / (fabsf(tau) + sqrtf(1.0f + tau * tau));
        float c = 1.0f / sqrtf(1.0f + tt * tt);
        float s = tt * c;
#pragma unroll
        for (int i = 0; i < 3; i++) {
            float Sip = S[i][p], Siq = S[i][q];
            S[i][p] = c * Sip - s * Siq;
            S[i][q] = s * Sip + c * Siq;
        }
#pragma unroll
        for (int i = 0; i < 3; i++) {
            float Spi = S[p][i], Sqi = S[q][i];
            S[p][i] = c * Spi - s * Sqi;
            S[q][i] = s * Spi + c * Sqi;
        }
#pragma unroll
        for (int i = 0; i < 3; i++) {
            float Vip = V[i][p], Viq = V[i][q];
            V[i][p] = c * Vip - s * Viq;
            V[i][q] = s * Vip + c * Viq;
        }
    }
}

template <int A, int Bc>
__device__ __forceinline__ void sort_pair(float lam[3], float V[3][3]) {
    if (lam[A] < lam[Bc]) {
        float tl = lam[A]; lam[A] = lam[Bc]; lam[Bc] = tl;
#pragma unroll
        for (int i = 0; i < 3; i++) {
            float tv = V[i][A]; V[i][A] = V[i][Bc]; V[i][Bc] = tv;
        }
    }
}

__device__ __forceinline__ void project_and_store(const float M[3][3],
                                                  float t0, float t1, float t2,
                                                  float* outp) {
    float S[3][3];
#pragma unroll
    for (int i = 0; i < 3; i++)
#pragma unroll
        for (int j = 0; j < 3; j++)
            S[i][j] = M[0][i] * M[0][j] + M[1][i] * M[1][j] + M[2][i] * M[2][j];
    float V[3][3] = {{1, 0, 0}, {0, 1, 0}, {0, 0, 1}};

#pragma unroll
    for (int sweep = 0; sweep < 4; sweep++) {
        jacobi_rot<0, 1>(S, V);
        jacobi_rot<0, 2>(S, V);
        jacobi_rot<1, 2>(S, V);
    }

    float lam[3] = {S[0][0], S[1][1], S[2][2]};
    sort_pair<0, 1>(lam, V);
    sort_pair<1, 2>(lam, V);
    sort_pair<0, 1>(lam, V);

    float detV = V[0][0] * (V[1][1] * V[2][2] - V[1][2] * V[2][1]) -
                 V[0][1] * (V[1][0] * V[2][2] - V[1][2] * V[2][0]) +
                 V[0][2] * (V[1][0] * V[2][1] - V[1][1] * V[2][0]);
    if (detV < 0.0f) { V[0][2] = -V[0][2]; V[1][2] = -V[1][2]; V[2][2] = -V[2][2]; }

    float Bm[3][3];
#pragma unroll
    for (int i = 0; i < 3; i++)
#pragma unroll
        for (int j = 0; j < 3; j++)
            Bm[i][j] = M[i][0] * V[0][j] + M[i][1] * V[1][j] + M[i][2] * V[2][j];

    float u0[3] = {Bm[0][0], Bm[1][0], Bm[2][0]};
    float n0 = u0[0] * u0[0] + u0[1] * u0[1] + u0[2] * u0[2];
    float rn0 = 1.0f / sqrtf(fmaxf(n0, 1e-24f));
    u0[0] *= rn0; u0[1] *= rn0; u0[2] *= rn0;

    float b1[3] = {Bm[0][1], Bm[1][1], Bm[2][1]};
    float d01 = u0[0] * b1[0] + u0[1] * b1[1] + u0[2] * b1[2];
    float u1[3] = {b1[0] - d01 * u0[0], b1[1] - d01 * u0[1], b1[2] - d01 * u0[2]};
    float n1 = u1[0] * u1[0] + u1[1] * u1[1] + u1[2] * u1[2];
    float rn1 = 1.0f / sqrtf(fmaxf(n1, 1e-24f));
    u1[0] *= rn1; u1[1] *= rn1; u1[2] *= rn1;

    float u2[3] = {u0[1] * u1[2] - u0[2] * u1[1],
                   u0[2] * u1[0] - u0[0] * u1[2],
                   u0[0] * u1[1] - u0[1] * u1[0]};

    float R[9];
#pragma unroll
    for (int i = 0; i < 3; i++) {
        float Ui0 = (i == 0 ? u0[0] : (i == 1 ? u0[1] : u0[2]));
        float Ui1 = (i == 0 ? u1[0] : (i == 1 ? u1[1] : u1[2]));
        float Ui2 = (i == 0 ? u2[0] : (i == 1 ? u2[1] : u2[2]));
#pragma unroll
        for (int j = 0; j < 3; j++)
            R[i * 3 + j] = Ui0 * V[j][0] + Ui1 * V[j][1] + Ui2 * V[j][2];
    }

    v4f* o4 = (v4f*)outp;
    o4[0] = (v4f){R[0], R[1], R[2], R[3]};
    o4[1] = (v4f){R[4], R[5], R[6], R[7]};
    o4[2] = (v4f){R[8], t0, t1, t2};
}

// ---------------------------------------------------------------------------
// Kernel 1: repack frames -> fp32, one 64B row per residue:
// [r0..r8, t0..t2, pad*4]. (fp16 failed R6: Kabsch amplifies rot error ~100x.)
// ---------------------------------------------------------------------------
__global__ __launch_bounds__(256) void repack_kernel(
    const float* __restrict__ frames_rot,    // [B*N, 9]
    const float* __restrict__ frames_trans,  // [B*N, 3]
    float* __restrict__ pk)                  // [B*N, 16]
{
    int row = blockIdx.x * 256 + threadIdx.x;
    const float* fr = frames_rot + (size_t)row * 9;
    const float* ft = frames_trans + (size_t)row * 3;
    v4f* o = (v4f*)(pk + (size_t)row * 16);
    o[0] = (v4f){fr[0], fr[1], fr[2], fr[3]};
    o[1] = (v4f){fr[4], fr[5], fr[6], fr[7]};
    o[2] = (v4f){fr[8], ft[0], ft[1], ft[2]};
}

// ---------------------------------------------------------------------------
// Kernel 2: R8's champion accumulation (best measured: 169.5us total) with
// the SO(3) solve FUSED into the wave tail — removes the solve launch, the
// 8MB acc round-trip, and one launch gap.
//
// One wave = 2 elems; lane L: h = L>>5 (elem half), k = L&31 (neighbor).
// Streams staged fully coalesced into WAVE-PRIVATE LDS (768 f/wave), no
// __syncthreads anywhere (wave-synchronous lgkmcnt orders write->read).
// Unpadded strides give <=2-way (free) banking (9k%32, 3k%32 cover all
// residues). Butterfly over 32 lanes, then lanes k==0 (2 per wave) run the
// Jacobi-Kabsch projection under exec mask and store straight to out.
//
// Falsified across R3-R11 (all land 39-45us accum): txn count (R7 coop
// gather, 12x fewer lines: no change), barriers (R5/R7 vs R8), reduce cost
// (R9/R10), staging wait-chain (R11 zero-LDS: slightly worse). Time tracks
// total wave count; 32K waves is the best point. This round only strips
// pipeline overhead around the proven body.
//
// NOTE: NO min-waves pin. R4's __launch_bounds__(256,8) capped VGPRs at 32
// -> scratch spills -> +178MB HBM writes.
// ---------------------------------------------------------------------------
__global__ __launch_bounds__(256) void accum_solve_kernel(
    const float* __restrict__ pk,         // [B*N,16] packed fp32 frames
    const float* __restrict__ pair_rot,   // [B,N,K,9]
    const float* __restrict__ pair_trans, // [B,N,K,3]
    const float* __restrict__ conf,       // [B,N,K]
    const int* __restrict__ topo,         // [B,N,K]
    float* __restrict__ out)              // [B*N,12]
{
    __shared__ float lds[4 * 768];  // 4 waves x (576 rot + 192 trans) = 12.3KB

    int tid = threadIdx.x;
    int wid = tid >> 6;   // wave in block 0..3
    int L = tid & 63;     // lane in wave
    int bid = blockIdx.x; // 0..8191

    // XCD-pinned batch swizzle: XCD x serves batches {x, x+8} -> pk slice
    // (2 x 256KB) stays L2-resident per XCD.
    int xcd = bid & 7;
    int slot = bid >> 3;                    // 0..1023
    int batch = xcd + ((slot >> 9) << 3);   // 0..15
    int within = slot & 511;                // 0..511
    int elem0 = batch * N_RES + within * 8 + wid * 2;  // wave's first elem

    int h = L >> 5;       // elem half 0/1
    int k = L & 31;       // owned neighbor
    int elem_g = elem0 + h;

    float* wlds = lds + wid * 768;  // wave-private: rot [0,576), trans [576,768)

    // --- conf/topo: one inst each, 64 consecutive values (2 elems x K). ---
    size_t nidx = (size_t)elem0 * KNB + L;
    float w = __builtin_nontemporal_load(conf + nidx);
    int j = __builtin_nontemporal_load(topo + nidx);

    // --- Stage pair_rot: 2 elems x 288 floats = 144 v4f, fully coalesced. ---
    const v4f* rg = (const v4f*)(pair_rot + (size_t)elem0 * (KNB * 9));
    for (int s = L; s < 144; s += 64) {
        v4f v = __builtin_nontemporal_load(rg + s);
        *(v4f*)(wlds + 4 * s) = v;
    }
    // --- Stage pair_trans: 2 elems x 96 floats = 48 v4f. ---
    const v4f* tg = (const v4f*)(pair_trans + (size_t)elem0 * (KNB * 3));
    if (L < 48) {
        v4f v = __builtin_nontemporal_load(tg + L);
        *(v4f*)(wlds + 576 + 4 * L) = v;
    }

    // --- Gather own frame row: 3 aligned dwordx4 from 64B row (L2-hot). ---
    const v4f* row = (const v4f*)(pk + ((size_t)batch * N_RES + (size_t)j) * 16);
    v4f fa = row[0], fb = row[1], fc = row[2];
    float r[9] = {fa.x, fa.y, fa.z, fa.w, fb.x, fb.y, fb.z, fb.w, fc.x};
    float tj0 = fc.y, tj1 = fc.z, tj2 = fc.w;

    // --- Read own pair record from wave-private LDS (2-way banks = free). ---
    const float* pr = wlds + h * 288 + k * 9;
    float p[9];
#pragma unroll
    for (int c = 0; c < 9; c++) p[c] = pr[c];
    const float* pt = wlds + 576 + h * 96 + k * 3;
    float q0 = pt[0], q1 = pt[1], q2 = pt[2];

    // --- Compute w * (Rj @ pr) and w * (Rj @ pt + tj). ---
    float Macc[9], tacc[3];
#pragma unroll
    for (int i = 0; i < 3; i++) {
#pragma unroll
        for (int l = 0; l < 3; l++) {
            Macc[i * 3 + l] = w * (r[i * 3 + 0] * p[0 * 3 + l] +
                                   r[i * 3 + 1] * p[1 * 3 + l] +
                                   r[i * 3 + 2] * p[2 * 3 + l]);
        }
        float tji = (i == 0 ? tj0 : (i == 1 ? tj1 : tj2));
        tacc[i] = w * (r[i * 3 + 0] * q0 + r[i * 3 + 1] * q1 +
                       r[i * 3 + 2] * q2 + tji);
    }
    float wsum = w;

    // --- Butterfly reduce over the 32 lanes of this elem half. ---
#pragma unroll
    for (int st = 1; st <= 16; st <<= 1) {
#pragma unroll
        for (int i = 0; i < 9; i++) Macc[i] += __shfl_xor(Macc[i], st);
#pragma unroll
        for (int i = 0; i < 3; i++) tacc[i] += __shfl_xor(tacc[i], st);
        wsum += __shfl_xor(wsum, st);
    }

    // --- Fused solve: lanes 0 and 32 (one per elem) project + store. ---
    if (k == 0) {
        float inv_w = 1.0f / fmaxf(wsum, 1e-20f);
        float M[3][3] = {{Macc[0] * inv_w, Macc[1] * inv_w, Macc[2] * inv_w},
                         {Macc[3] * inv_w, Macc[4] * inv_w, Macc[5] * inv_w},
                         {Macc[6] * inv_w, Macc[7] * inv_w, Macc[8] * inv_w}};
        project_and_store(M, tacc[0] * inv_w, tacc[1] * inv_w, tacc[2] * inv_w,
                          out + (size_t)elem_g * 12);
    }
}

// ---------------------------------------------------------------------------
// Fallback fused kernel (only if ws too small) — Round-2 validated path.
// ---------------------------------------------------------------------------
__global__ __launch_bounds__(256) void fused_kernel(
    const float* __restrict__ frames_rot, const float* __restrict__ frames_trans,
    const float* __restrict__ pair_rot, const float* __restrict__ pair_trans,
    const float* __restrict__ conf, const int* __restrict__ topo,
    float* __restrict__ out)
{
    int tid = threadIdx.x;
    int bid = blockIdx.x;
    int xcd = bid & 7;
    int slot = bid >> 3;
    int batch = xcd + ((slot >> 7) << 3);
    int chunk = slot & 127;
    int elem = batch * N_RES + chunk * 32 + (tid >> 3);
    int t = tid & 7;

    const float* fr_b = frames_rot + (size_t)batch * N_RES * 9;
    const float* ft_b = frames_trans + (size_t)batch * N_RES * 3;

    size_t kbase = (size_t)elem * KNB + (size_t)t * 4;
    const v4f* pr4 = (const v4f*)(pair_rot + kbase * 9);
    const v4f* pt4 = (const v4f*)(pair_trans + kbase * 3);
    const v4f* cf4 = (const v4f*)(conf + kbase);
    const v4i* tp4 = (const v4i*)(topo + kbase);

    float prl[36];
#pragma unroll
    for (int i = 0; i < 9; i++) {
        v4f v = __builtin_nontemporal_load(pr4 + i);
        prl[4 * i] = v.x; prl[4 * i + 1] = v.y; prl[4 * i + 2] = v.z; prl[4 * i + 3] = v.w;
    }
    float ptl[12];
#pragma unroll
    for (int i = 0; i < 3; i++) {
        v4f v = __builtin_nontemporal_load(pt4 + i);
        ptl[4 * i] = v.x; ptl[4 * i + 1] = v.y; ptl[4 * i + 2] = v.z; ptl[4 * i + 3] = v.w;
    }
    v4f wv = __builtin_nontemporal_load(cf4);
    float wl[4] = {wv.x, wv.y, wv.z, wv.w};
    v4i jv = __builtin_nontemporal_load(tp4);
    int jl[4] = {jv.x, jv.y, jv.z, jv.w};

    float Macc[9] = {0, 0, 0, 0, 0, 0, 0, 0, 0};
    float tacc[3] = {0, 0, 0};
    float wsum = 0.0f;

#pragma unroll
    for (int kk = 0; kk < 4; kk++) {
        int j = jl[kk];
        const float* Rj = fr_b + j * 9;
        const float* Tj = ft_b + j * 3;
        float r[9];
#pragma unroll
        for (int i = 0; i < 9; i++) r[i] = Rj[i];
        float tj[3];
#pragma unroll
        for (int i = 0; i < 3; i++) tj[i] = Tj[i];
        float w = wl[kk];
        const float* pr = prl + kk * 9;
        const float* pt = ptl + kk * 3;
#pragma unroll
        for (int i = 0; i < 3; i++) {
#pragma unroll
            for (int l = 0; l < 3; l++) {
                float cij = r[i * 3] * pr[l] + r[i * 3 + 1] * pr[3 + l] + r[i * 3 + 2] * pr[6 + l];
                Macc[i * 3 + l] += w * cij;
            }
            float ct = r[i * 3] * pt[0] + r[i * 3 + 1] * pt[1] + r[i * 3 + 2] * pt[2] + tj[i];
            tacc[i] += w * ct;
        }
        wsum += w;
    }

#pragma unroll
    for (int st = 1; st <= 4; st <<= 1) {
#pragma unroll
        for (int i = 0; i < 9; i++) Macc[i] += __shfl_xor(Macc[i], st);
#pragma unroll
        for (int i = 0; i < 3; i++) tacc[i] += __shfl_xor(tacc[i], st);
        wsum += __shfl_xor(wsum, st);
    }

    float inv_w = 1.0f / fmaxf(wsum, 1e-20f);
    float M[3][3];
#pragma unroll
    for (int i = 0; i < 3; i++)
#pragma unroll
        for (int j = 0; j < 3; j++) M[i][j] = Macc[i * 3 + j] * inv_w;

    if (t == 0)
        project_and_store(M, tacc[0] * inv_w, tacc[1] * inv_w, tacc[2] * inv_w,
                          out + (size_t)elem * 12);
}

extern "C" void kernel_launch(void* const* d_in, const int* in_sizes, int n_in,
                              void* d_out, int out_size, void* d_ws, size_t ws_size,
                              hipStream_t stream) {
    const float* frames_rot = (const float*)d_in[0];
    const float* frames_trans = (const float*)d_in[1];
    const float* pair_rot = (const float*)d_in[2];
    const float* pair_trans = (const float*)d_in[3];
    const float* conf = (const float*)d_in[4];
    const int* topo = (const int*)d_in[5];
    float* out = (float*)d_out;

    const size_t PK_BYTES = (size_t)BN_TOTAL * 16 * sizeof(float);  // 4MB

    if (ws_size >= PK_BYTES) {
        float* pk = (float*)d_ws;
        hipLaunchKernelGGL(repack_kernel, dim3(BN_TOTAL / 256), dim3(256), 0, stream,
                           frames_rot, frames_trans, pk);
        // one wave per 2 elems, 4 waves/block -> 65536/8 = 8192 blocks (32K waves)
        hipLaunchKernelGGL(accum_solve_kernel, dim3(BN_TOTAL / 8), dim3(256), 0, stream,
                           pk, pair_rot, pair_trans, conf, topo, out);
    } else {
        hipLaunchKernelGGL(fused_kernel, dim3(BN_TOTAL * 8 / 256), dim3(256), 0, stream,
                           frames_rot, frames_trans, pair_rot, pair_trans, conf, topo, out);
    }
}

// Round 13
// 168.821 us; speedup vs baseline: 1.4607x; 1.4607x over previous
//
#include <hip/hip_runtime.h>
#include <math.h>

#define N_RES 4096
#define KNB 32
#define BN_TOTAL 65536  // B*N = 16*4096

typedef float v4f __attribute__((ext_vector_type(4)));
typedef int v4i __attribute__((ext_vector_type(4)));

// ---------------------------------------------------------------------------
// SO(3) projection (cyclic Jacobi on M^T M + Gram-Schmidt for U) — validated.
// ---------------------------------------------------------------------------
template <int p, int q>
__device__ __forceinline__ void jacobi_rot(float S[3][3], float V[3][3]) {
    float apq = S[p][q];
    if (fabsf(apq) > 1e-20f) {
        float app = S[p][p], aqq = S[q][q];
        float tau = (aqq - app) / (2.0f * apq);
        float tt = (tau >= 0.0f ? 1.0f : -1.0f) / (fabsf(tau) + sqrtf(1.0f + tau * tau));
        float c = 1.0f / sqrtf(1.0f + tt * tt);
        float s = tt * c;
#pragma unroll
        for (int i = 0; i < 3; i++) {
            float Sip = S[i][p], Siq = S[i][q];
            S[i][p] = c * Sip - s * Siq;
            S[i][q] = s * Sip + c * Siq;
        }
#pragma unroll
        for (int i = 0; i < 3; i++) {
            float Spi = S[p][i], Sqi = S[q][i];
            S[p][i] = c * Spi - s * Sqi;
            S[q][i] = s * Spi + c * Sqi;
        }
#pragma unroll
        for (int i = 0; i < 3; i++) {
            float Vip = V[i][p], Viq = V[i][q];
            V[i][p] = c * Vip - s * Viq;
            V[i][q] = s * Vip + c * Viq;
        }
    }
}

template <int A, int Bc>
__device__ __forceinline__ void sort_pair(float lam[3], float V[3][3]) {
    if (lam[A] < lam[Bc]) {
        float tl = lam[A]; lam[A] = lam[Bc]; lam[Bc] = tl;
#pragma unroll
        for (int i = 0; i < 3; i++) {
            float tv = V[i][A]; V[i][A] = V[i][Bc]; V[i][Bc] = tv;
        }
    }
}

__device__ __forceinline__ void project_and_store(const float M[3][3],
                                                  float t0, float t1, float t2,
                                                  float* outp) {
    float S[3][3];
#pragma unroll
    for (int i = 0; i < 3; i++)
#pragma unroll
        for (int j = 0; j < 3; j++)
            S[i][j] = M[0][i] * M[0][j] + M[1][i] * M[1][j] + M[2][i] * M[2][j];
    float V[3][3] = {{1, 0, 0}, {0, 1, 0}, {0, 0, 1}};

#pragma unroll
    for (int sweep = 0; sweep < 4; sweep++) {
        jacobi_rot<0, 1>(S, V);
        jacobi_rot<0, 2>(S, V);
        jacobi_rot<1, 2>(S, V);
    }

    float lam[3] = {S[0][0], S[1][1], S[2][2]};
    sort_pair<0, 1>(lam, V);
    sort_pair<1, 2>(lam, V);
    sort_pair<0, 1>(lam, V);

    float detV = V[0][0] * (V[1][1] * V[2][2] - V[1][2] * V[2][1]) -
                 V[0][1] * (V[1][0] * V[2][2] - V[1][2] * V[2][0]) +
                 V[0][2] * (V[1][0] * V[2][1] - V[1][1] * V[2][0]);
    if (detV < 0.0f) { V[0][2] = -V[0][2]; V[1][2] = -V[1][2]; V[2][2] = -V[2][2]; }

    float Bm[3][3];
#pragma unroll
    for (int i = 0; i < 3; i++)
#pragma unroll
        for (int j = 0; j < 3; j++)
            Bm[i][j] = M[i][0] * V[0][j] + M[i][1] * V[1][j] + M[i][2] * V[2][j];

    float u0[3] = {Bm[0][0], Bm[1][0], Bm[2][0]};
    float n0 = u0[0] * u0[0] + u0[1] * u0[1] + u0[2] * u0[2];
    float rn0 = 1.0f / sqrtf(fmaxf(n0, 1e-24f));
    u0[0] *= rn0; u0[1] *= rn0; u0[2] *= rn0;

    float b1[3] = {Bm[0][1], Bm[1][1], Bm[2][1]};
    float d01 = u0[0] * b1[0] + u0[1] * b1[1] + u0[2] * b1[2];
    float u1[3] = {b1[0] - d01 * u0[0], b1[1] - d01 * u0[1], b1[2] - d01 * u0[2]};
    float n1 = u1[0] * u1[0] + u1[1] * u1[1] + u1[2] * u1[2];
    float rn1 = 1.0f / sqrtf(fmaxf(n1, 1e-24f));
    u1[0] *= rn1; u1[1] *= rn1; u1[2] *= rn1;

    float u2[3] = {u0[1] * u1[2] - u0[2] * u1[1],
                   u0[2] * u1[0] - u0[0] * u1[2],
                   u0[0] * u1[1] - u0[1] * u1[0]};

    float R[9];
#pragma unroll
    for (int i = 0; i < 3; i++) {
        float Ui0 = (i == 0 ? u0[0] : (i == 1 ? u0[1] : u0[2]));
        float Ui1 = (i == 0 ? u1[0] : (i == 1 ? u1[1] : u1[2]));
        float Ui2 = (i == 0 ? u2[0] : (i == 1 ? u2[1] : u2[2]));
#pragma unroll
        for (int j = 0; j < 3; j++)
            R[i * 3 + j] = Ui0 * V[j][0] + Ui1 * V[j][1] + Ui2 * V[j][2];
    }

    v4f* o4 = (v4f*)outp;
    o4[0] = (v4f){R[0], R[1], R[2], R[3]};
    o4[1] = (v4f){R[4], R[5], R[6], R[7]};
    o4[2] = (v4f){R[8], t0, t1, t2};
}

// ---------------------------------------------------------------------------
// Kernel 1: repack frames -> fp32, one 64B row per residue:
// [r0..r8, t0..t2, pad*4]. (fp16 failed R6: Kabsch amplifies rot error ~100x.)
// ---------------------------------------------------------------------------
__global__ __launch_bounds__(256) void repack_kernel(
    const float* __restrict__ frames_rot,    // [B*N, 9]
    const float* __restrict__ frames_trans,  // [B*N, 3]
    float* __restrict__ pk)                  // [B*N, 16]
{
    int row = blockIdx.x * 256 + threadIdx.x;
    const float* fr = frames_rot + (size_t)row * 9;
    const float* ft = frames_trans + (size_t)row * 3;
    v4f* o = (v4f*)(pk + (size_t)row * 16);
    o[0] = (v4f){fr[0], fr[1], fr[2], fr[3]};
    o[1] = (v4f){fr[4], fr[5], fr[6], fr[7]};
    o[2] = (v4f){fr[8], ft[0], ft[1], ft[2]};
}

// ---------------------------------------------------------------------------
// Kernel 2: CHAMPION (R8, 169.5us total): barrier-free accumulation,
// 32768 waves. One wave = 2 elems; lane L: h = L>>5 (elem), k = L&31
// (neighbor). Streams staged fully coalesced into WAVE-PRIVATE LDS
// (768 f/wave), no __syncthreads (wave-synchronous lgkmcnt orders
// write->read). Unpadded strides: 9k%32 / 3k%32 cover all residues ->
// <=2-way (free) banking. Butterfly over 32 lanes; lane k==0 stores sums.
//
// Session falsification record (all alternatives 175-247us total):
//  - R7 coop gather (12x fewer gather lines): no change -> txns not binding
//  - R5/R7 chunked barriers vs R8 none: barriers cost ~6us
//  - R9 8-elem/wave (4x fewer waves, cheaper reduce): regressed -> wave count
//  - R10 partials offload (reduce work moved out): round-trip cost > savings
//  - R11 zero-LDS direct loads (no staging chain): no gain
//  - R12 fused solve in wave tail: +100us (2/64-lane divergent projection)
// Time tracks total wave count; latency-bound under harness-flushed L3.
//
// NOTE: NO min-waves pin. R4's __launch_bounds__(256,8) capped VGPRs at 32
// -> scratch spills -> +178MB HBM writes.
// ---------------------------------------------------------------------------
__global__ __launch_bounds__(256) void accum_kernel(
    const float* __restrict__ pk,         // [B*N,16] packed fp32 frames
    const float* __restrict__ pair_rot,   // [B,N,K,9]
    const float* __restrict__ pair_trans, // [B,N,K,3]
    const float* __restrict__ conf,       // [B,N,K]
    const int* __restrict__ topo,         // [B,N,K]
    float* __restrict__ acc)              // [B*N,16]
{
    __shared__ float lds[4 * 768];  // 4 waves x (576 rot + 192 trans) = 12.3KB

    int tid = threadIdx.x;
    int wid = tid >> 6;   // wave in block 0..3
    int L = tid & 63;     // lane in wave
    int bid = blockIdx.x; // 0..8191

    // XCD-pinned batch swizzle: XCD x serves batches {x, x+8} -> pk slice
    // (2 x 256KB) stays L2-resident per XCD.
    int xcd = bid & 7;
    int slot = bid >> 3;                    // 0..1023
    int batch = xcd + ((slot >> 9) << 3);   // 0..15
    int within = slot & 511;                // 0..511
    int elem0 = batch * N_RES + within * 8 + wid * 2;  // wave's first elem

    int h = L >> 5;       // elem half 0/1
    int k = L & 31;       // owned neighbor
    int elem_g = elem0 + h;

    float* wlds = lds + wid * 768;  // wave-private: rot [0,576), trans [576,768)

    // --- conf/topo: one inst each, 64 consecutive values (2 elems x K). ---
    size_t nidx = (size_t)elem0 * KNB + L;
    float w = __builtin_nontemporal_load(conf + nidx);
    int j = __builtin_nontemporal_load(topo + nidx);

    // --- Stage pair_rot: 2 elems x 288 floats = 144 v4f, fully coalesced. ---
    const v4f* rg = (const v4f*)(pair_rot + (size_t)elem0 * (KNB * 9));
    for (int s = L; s < 144; s += 64) {
        v4f v = __builtin_nontemporal_load(rg + s);
        *(v4f*)(wlds + 4 * s) = v;
    }
    // --- Stage pair_trans: 2 elems x 96 floats = 48 v4f. ---
    const v4f* tg = (const v4f*)(pair_trans + (size_t)elem0 * (KNB * 3));
    if (L < 48) {
        v4f v = __builtin_nontemporal_load(tg + L);
        *(v4f*)(wlds + 576 + 4 * L) = v;
    }

    // --- Gather own frame row: 3 aligned dwordx4 from 64B row (L2-hot). ---
    const v4f* row = (const v4f*)(pk + ((size_t)batch * N_RES + (size_t)j) * 16);
    v4f fa = row[0], fb = row[1], fc = row[2];
    float r[9] = {fa.x, fa.y, fa.z, fa.w, fb.x, fb.y, fb.z, fb.w, fc.x};
    float tj0 = fc.y, tj1 = fc.z, tj2 = fc.w;

    // --- Read own pair record from wave-private LDS (2-way banks = free). ---
    const float* pr = wlds + h * 288 + k * 9;
    float p[9];
#pragma unroll
    for (int c = 0; c < 9; c++) p[c] = pr[c];
    const float* pt = wlds + 576 + h * 96 + k * 3;
    float q0 = pt[0], q1 = pt[1], q2 = pt[2];

    // --- Compute w * (Rj @ pr) and w * (Rj @ pt + tj). ---
    float Macc[9], tacc[3];
#pragma unroll
    for (int i = 0; i < 3; i++) {
#pragma unroll
        for (int l = 0; l < 3; l++) {
            Macc[i * 3 + l] = w * (r[i * 3 + 0] * p[0 * 3 + l] +
                                   r[i * 3 + 1] * p[1 * 3 + l] +
                                   r[i * 3 + 2] * p[2 * 3 + l]);
        }
        float tji = (i == 0 ? tj0 : (i == 1 ? tj1 : tj2));
        tacc[i] = w * (r[i * 3 + 0] * q0 + r[i * 3 + 1] * q1 +
                       r[i * 3 + 2] * q2 + tji);
    }
    float wsum = w;

    // --- Butterfly reduce over the 32 lanes of this elem half. ---
#pragma unroll
    for (int st = 1; st <= 16; st <<= 1) {
#pragma unroll
        for (int i = 0; i < 9; i++) Macc[i] += __shfl_xor(Macc[i], st);
#pragma unroll
        for (int i = 0; i < 3; i++) tacc[i] += __shfl_xor(tacc[i], st);
        wsum += __shfl_xor(wsum, st);
    }

    if (k == 0) {  // lanes 0 and 32 each store one elem's sums
        v4f* o = (v4f*)(acc + (size_t)elem_g * 16);
        o[0] = (v4f){Macc[0], Macc[1], Macc[2], Macc[3]};
        o[1] = (v4f){Macc[4], Macc[5], Macc[6], Macc[7]};
        o[2] = (v4f){Macc[8], tacc[0], tacc[1], tacc[2]};
        o[3] = (v4f){wsum, 0.0f, 0.0f, 0.0f};
    }
}

// ---------------------------------------------------------------------------
// Kernel 3: per-element SO(3) solve, 1 thread/elem — DENSE (all 64 lanes
// active; R12 proved the fused 2/64-lane variant costs ~100us of divergent
// VALU). Reads its elem's 64B acc record, projects, stores 48B.
// ---------------------------------------------------------------------------
__global__ __launch_bounds__(256) void solve_kernel(
    const float* __restrict__ acc,  // [B*N,16]
    float* __restrict__ out)        // [B*N,12]
{
    int elem = blockIdx.x * 256 + threadIdx.x;
    const v4f* a4 = (const v4f*)(acc + (size_t)elem * 16);
    v4f A0 = a4[0], A1 = a4[1], A2 = a4[2], A3 = a4[3];
    float inv_w = 1.0f / fmaxf(A3.x, 1e-20f);
    float M[3][3] = {{A0.x * inv_w, A0.y * inv_w, A0.z * inv_w},
                     {A0.w * inv_w, A1.x * inv_w, A1.y * inv_w},
                     {A1.z * inv_w, A1.w * inv_w, A2.x * inv_w}};
    float t0 = A2.y * inv_w, t1 = A2.z * inv_w, t2 = A2.w * inv_w;
    project_and_store(M, t0, t1, t2, out + (size_t)elem * 12);
}

// ---------------------------------------------------------------------------
// Fallback fused kernel (only if ws too small) — Round-2 validated path.
// ---------------------------------------------------------------------------
__global__ __launch_bounds__(256) void fused_kernel(
    const float* __restrict__ frames_rot, const float* __restrict__ frames_trans,
    const float* __restrict__ pair_rot, const float* __restrict__ pair_trans,
    const float* __restrict__ conf, const int* __restrict__ topo,
    float* __restrict__ out)
{
    int tid = threadIdx.x;
    int bid = blockIdx.x;
    int xcd = bid & 7;
    int slot = bid >> 3;
    int batch = xcd + ((slot >> 7) << 3);
    int chunk = slot & 127;
    int elem = batch * N_RES + chunk * 32 + (tid >> 3);
    int t = tid & 7;

    const float* fr_b = frames_rot + (size_t)batch * N_RES * 9;
    const float* ft_b = frames_trans + (size_t)batch * N_RES * 3;

    size_t kbase = (size_t)elem * KNB + (size_t)t * 4;
    const v4f* pr4 = (const v4f*)(pair_rot + kbase * 9);
    const v4f* pt4 = (const v4f*)(pair_trans + kbase * 3);
    const v4f* cf4 = (const v4f*)(conf + kbase);
    const v4i* tp4 = (const v4i*)(topo + kbase);

    float prl[36];
#pragma unroll
    for (int i = 0; i < 9; i++) {
        v4f v = __builtin_nontemporal_load(pr4 + i);
        prl[4 * i] = v.x; prl[4 * i + 1] = v.y; prl[4 * i + 2] = v.z; prl[4 * i + 3] = v.w;
    }
    float ptl[12];
#pragma unroll
    for (int i = 0; i < 3; i++) {
        v4f v = __builtin_nontemporal_load(pt4 + i);
        ptl[4 * i] = v.x; ptl[4 * i + 1] = v.y; ptl[4 * i + 2] = v.z; ptl[4 * i + 3] = v.w;
    }
    v4f wv = __builtin_nontemporal_load(cf4);
    float wl[4] = {wv.x, wv.y, wv.z, wv.w};
    v4i jv = __builtin_nontemporal_load(tp4);
    int jl[4] = {jv.x, jv.y, jv.z, jv.w};

    float Macc[9] = {0, 0, 0, 0, 0, 0, 0, 0, 0};
    float tacc[3] = {0, 0, 0};
    float wsum = 0.0f;

#pragma unroll
    for (int kk = 0; kk < 4; kk++) {
        int j = jl[kk];
        const float* Rj = fr_b + j * 9;
        const float* Tj = ft_b + j * 3;
        float r[9];
#pragma unroll
        for (int i = 0; i < 9; i++) r[i] = Rj[i];
        float tj[3];
#pragma unroll
        for (int i = 0; i < 3; i++) tj[i] = Tj[i];
        float w = wl[kk];
        const float* pr = prl + kk * 9;
        const float* pt = ptl + kk * 3;
#pragma unroll
        for (int i = 0; i < 3; i++) {
#pragma unroll
            for (int l = 0; l < 3; l++) {
                float cij = r[i * 3] * pr[l] + r[i * 3 + 1] * pr[3 + l] + r[i * 3 + 2] * pr[6 + l];
                Macc[i * 3 + l] += w * cij;
            }
            float ct = r[i * 3] * pt[0] + r[i * 3 + 1] * pt[1] + r[i * 3 + 2] * pt[2] + tj[i];
            tacc[i] += w * ct;
        }
        wsum += w;
    }

#pragma unroll
    for (int st = 1; st <= 4; st <<= 1) {
#pragma unroll
        for (int i = 0; i < 9; i++) Macc[i] += __shfl_xor(Macc[i], st);
#pragma unroll
        for (int i = 0; i < 3; i++) tacc[i] += __shfl_xor(tacc[i], st);
        wsum += __shfl_xor(wsum, st);
    }

    float inv_w = 1.0f / fmaxf(wsum, 1e-20f);
    float M[3][3];
#pragma unroll
    for (int i = 0; i < 3; i++)
#pragma unroll
        for (int j = 0; j < 3; j++) M[i][j] = Macc[i * 3 + j] * inv_w;

    if (t == 0)
        project_and_store(M, tacc[0] * inv_w, tacc[1] * inv_w, tacc[2] * inv_w,
                          out + (size_t)elem * 12);
}

extern "C" void kernel_launch(void* const* d_in, const int* in_sizes, int n_in,
                              void* d_out, int out_size, void* d_ws, size_t ws_size,
                              hipStream_t stream) {
    const float* frames_rot = (const float*)d_in[0];
    const float* frames_trans = (const float*)d_in[1];
    const float* pair_rot = (const float*)d_in[2];
    const float* pair_trans = (const float*)d_in[3];
    const float* conf = (const float*)d_in[4];
    const int* topo = (const int*)d_in[5];
    float* out = (float*)d_out;

    const size_t PK_BYTES = (size_t)BN_TOTAL * 16 * sizeof(float);   // 4MB
    const size_t ACC_BYTES = (size_t)BN_TOTAL * 16 * sizeof(float);  // 4MB
    const size_t need = PK_BYTES + ACC_BYTES;                        // 8MB

    if (ws_size >= need) {
        float* pk = (float*)d_ws;
        float* acc = (float*)((char*)d_ws + PK_BYTES);
        hipLaunchKernelGGL(repack_kernel, dim3(BN_TOTAL / 256), dim3(256), 0, stream,
                           frames_rot, frames_trans, pk);
        // one wave per 2 elems: 65536/2 waves / 4 per block = 8192 blocks
        hipLaunchKernelGGL(accum_kernel, dim3(BN_TOTAL / 8), dim3(256), 0, stream,
                           pk, pair_rot, pair_trans, conf, topo, acc);
        hipLaunchKernelGGL(solve_kernel, dim3(BN_TOTAL / 256), dim3(256), 0, stream,
                           acc, out);
    } else {
        hipLaunchKernelGGL(fused_kernel, dim3(BN_TOTAL * 8 / 256), dim3(256), 0, stream,
                           frames_rot, frames_trans, pair_rot, pair_trans, conf, topo, out);
    }
}